// Round 4
// baseline (244.226 us; speedup 1.0000x reference)
//
#include <hip/hip_runtime.h>

typedef unsigned short u16;
typedef __bf16 bf16x8 __attribute__((ext_vector_type(8)));
typedef float f32x4 __attribute__((ext_vector_type(4)));

// ---------- bf16 <-> f32 helpers (RNE) ----------
__device__ __forceinline__ u16 f2bf(float f) {
    union { float f; unsigned int u; } v; v.f = f;
    unsigned int u = v.u;
    return (u16)((u + 0x7FFFu + ((u >> 16) & 1u)) >> 16);
}

// ---------- async global->LDS, 16B per lane ----------
__device__ __forceinline__ void load_lds16(const void* g, void* l) {
    __builtin_amdgcn_global_load_lds(
        (const __attribute__((address_space(1))) unsigned int*)g,
        (__attribute__((address_space(3))) unsigned int*)l,
        16, 0, 0);
}

// MODE2 block classes in LPT (longest-first) dispatch order, BK128 units.
// Split tiles (mtile>=8): kh=0 takes (m+1)>>1 units from k=0, kh=1 takes the
// remaining (m+1)-((m+1)>>1) units. kh==2 means "full tile" (m+1 units).
// Sorted by descending work: 8,8,8,8,7,7,7,7,7,6,6,6,6,6,5,5,5,5,5,4,4,3,2,1.
__constant__ unsigned char cls_m[24] = {15,15,7,14,14,13,13,6,12,12,11,11,5,10,10,9,9,4,8,8,3,2,1,0};
__constant__ unsigned char cls_h[24] = { 0, 1,2, 1, 0, 0, 1,2, 1, 0, 0, 1,2, 1, 0,0,1,2,1,0,2,2,2,2};

// ---------------------------------------------------------------
// fused prep: 0..8191 cast x fp32->bf16; 8192..11263 transpose W;
// 11264..11295 zero rowsum (8192 floats).
// ---------------------------------------------------------------
__global__ void __launch_bounds__(256) prep_kernel(
    const float4* __restrict__ X, u16* __restrict__ xb,
    const float* __restrict__ Wq, const float* __restrict__ Wk,
    const float* __restrict__ Wv,
    u16* __restrict__ Oq, u16* __restrict__ Ok, u16* __restrict__ Ov,
    float* __restrict__ rowsum) {
    __shared__ float tile[32][33];
    const int bid = blockIdx.x, tid = threadIdx.x;
    if (bid < 8192) {
        int idx = bid * 256 + tid;
        float4 v = X[idx];
        ushort4 o;
        o.x = f2bf(v.x); o.y = f2bf(v.y); o.z = f2bf(v.z); o.w = f2bf(v.w);
        *(ushort4*)(xb + (size_t)idx * 4) = o;
    } else if (bid < 11264) {
        int id = bid - 8192;
        int zz = id >> 10;
        const float* W = (zz == 0) ? Wq : (zz == 1) ? Wk : Wv;
        u16* O = (zz == 0) ? Oq : (zz == 1) ? Ok : Ov;
        int n0 = (id & 31) * 32, k0 = ((id >> 5) & 31) * 32;
        int tx = tid & 31, ty = tid >> 5;
        #pragma unroll
        for (int j = 0; j < 32; j += 8)
            tile[ty + j][tx] = W[(size_t)(k0 + ty + j) * 1024 + n0 + tx];
        __syncthreads();
        #pragma unroll
        for (int j = 0; j < 32; j += 8)
            O[(size_t)(n0 + ty + j) * 1024 + k0 + tx] = f2bf(tile[tx][ty + j]);
    } else {
        rowsum[(bid - 11264) * 256 + tid] = 0.f;
    }
}

// ---------------------------------------------------------------
// combine: out[z][1024+r][:] = (out + P1) * inv(rowsum) for the
// split-K rows (1024..2047 per batch). 4096 blocks x 256 threads.
// ---------------------------------------------------------------
__global__ void __launch_bounds__(256) combine_kernel(
    const float4* __restrict__ P1, const float* __restrict__ rowsum,
    float4* __restrict__ out) {
    int b = blockIdx.x;                        // 0..4095
    int z = b >> 10;
    int i = (b & 1023) * 256 + threadIdx.x;    // 0..262143 float4 within z
    int r = i >> 8;                            // 256 float4 per row
    float inv = 1.0f / rowsum[z * 2048 + 1024 + r];
    size_t oi = (size_t)z * (2048 * 1024 / 4) + (1024 * 1024 / 4) + i;
    float4 a = out[oi];
    float4 p = P1[(size_t)z * (1024 * 1024 / 4) + i];
    a.x = (a.x + p.x) * inv;
    a.y = (a.y + p.y) * inv;
    a.z = (a.z + p.z) * inv;
    a.w = (a.w + p.w) * inv;
    out[oi] = a;
}

// ---------------------------------------------------------------
// NT bf16 GEMM, 128x128 tile, 512 threads = 8 waves (2x4 grid), each
// wave computes 64x32 (acc = 8 f32x4 -> 72 total V+AGPR -> 2 blocks/CU,
// the HW ceiling for this acc size per the 64/128/256 alloc steps).
// BK=128 single-buffer LDS (64 KiB): stage 8x16B/thread -> barrier ->
// 256 MFMAs -> barrier. Halves barrier count vs BK=64 to amortize the
// vmcnt(0)+lgkmcnt(0) drain (the known ~20% stall of this structure);
// occupancy is 2 blocks/CU either way (160/64 = 2), so the m132
// occupancy regression does not apply. XOR-swizzled 16B chunks per K32
// section: conflict-free. Per-mode LDS pad fingerprints modes in
// rocprof (65536 / 66048 / 66560 B).
//
// MODE 0: QKV projections (1536 blocks; z=0/1 -> Q/K, z=2 -> Vt[b][d][s]).
// MODE 1: P~ = exp(QK^T/32 - 12) into S, live causal tiles, rowsum
//         via shfl + one fp32 atomic per 16 lanes (768 blocks).
// MODE 2: O~ = P~ V; split-K (NO atomics) for mtile>=8 at BK128 grain:
//         kh=0 -> raw partial into P1 (dead xb), kh=1 -> raw into out;
//         full tiles -> normalized out. LPT order via cls_m/cls_h;
//         Vt XCD-local (768 blocks). combine_kernel merges rows 1024+.
// ---------------------------------------------------------------
template <int MODE>
__global__ void __launch_bounds__(512) gemm_nt(
    const u16* __restrict__ xb, const u16* __restrict__ WqT,
    const u16* __restrict__ WkT, const u16* __restrict__ WvT,
    u16* __restrict__ Q, u16* __restrict__ Kb,
    u16* __restrict__ Vt, u16* __restrict__ S,
    float* __restrict__ rowsum, float* __restrict__ out,
    float* __restrict__ P1) {

    int mtile, ntile, z, kbeg = 0, kiters, kh = 2;
    const u16 *A, *B;

    if (MODE == 0) {
        int L = blockIdx.x;                       // 1536 blocks
        int c = L & 7, t = (L >> 3) & 7, hi = L >> 6;
        int p = hi * 8 + c;                       // 0..191; mtile&7 == c
        z = p >> 6; mtile = p & 63; ntile = t;
        A = xb;
        B = (z == 0) ? WqT : (z == 1) ? WkT : WvT;
        kiters = 8;                               // K=1024, BK=128
    } else if (MODE == 1) {
        int id2 = blockIdx.x;                     // 768 blocks, 544 live
        z = id2 / 192;
        int r = id2 - z * 192;
        int c = r & 7, g = r >> 3;
        if (g <= c)            { mtile = c;     ntile = g; }
        else if (g < 2*c + 10) { mtile = c + 8; ntile = g - (c + 1); }
        else return;
        A = Q  + (size_t)z * (2048 * 1024);
        B = Kb + (size_t)z * (2048 * 1024);
        kiters = 8;
    } else {
        int L = blockIdx.x;                       // 768 blocks
        ntile = L & 7;                            // Vt XCD-local
        int j = L >> 3;
        z = j & 3;
        int ci = j >> 2;                          // 0..23, LPT class order
        mtile = cls_m[ci];
        kh = cls_h[ci];
        int u0 = (mtile + 1) >> 1;                // BK128 units in half 0
        if (kh == 0)      { kbeg = 0;  kiters = u0; }
        else if (kh == 1) { kbeg = u0; kiters = (mtile + 1) - u0; }
        else              { kbeg = 0;  kiters = mtile + 1; }
        A = S  + (size_t)z * (2048 * 2048);
        B = Vt + (size_t)z * (1024 * 2048);
    }

    const int LDA = (MODE == 2) ? 2048 : 1024;

    __shared__ __align__(16) u16 As[128 * 128];              // 4 K32 sections
    __shared__ __align__(16) u16 Bs[128 * 128 + MODE * 256]; // +fingerprint pad

    const int tid = threadIdx.x;
    const int lane = tid & 63;
    const int wave = tid >> 6;                   // 0..7
    const int wr = wave >> 2, wc = wave & 3;     // 2 x 4 wave grid

    // staging: 512 lanes cover 128 rows x 4 chunks of 16B per K32 section
    const int r0 = tid >> 2;                     // 0..127
    const int kb = (((tid & 3) ^ ((r0 >> 1) & 3))) * 16;   // swizzled chunk

    const char* gA = (const char*)(A + (size_t)(mtile * 128 + r0) * LDA) + kb + kbeg * 256;
    const char* gB = (const char*)(B + (size_t)(ntile * 128 + r0) * LDA) + kb + kbeg * 256;

    char* lA = (char*)As + tid * 16;             // section h at +h*8192 B
    char* lB = (char*)Bs + tid * 16;

    f32x4 acc[4][2] = {};

    const int quad = lane >> 4;
    const int l16 = lane & 15;
    const int ch = quad ^ ((l16 >> 1) & 3);      // de-swizzle on read
    const int aoff = (wr * 64 + l16) * 32 + ch * 8;
    const int boff = (wc * 32 + l16) * 32 + ch * 8;

    for (int kt = 0; kt < kiters; ++kt) {
        #pragma unroll
        for (int h = 0; h < 4; ++h) {
            load_lds16(gA + h * 64, lA + h * 8192);
            load_lds16(gB + h * 64, lB + h * 8192);
        }
        gA += 256; gB += 256;
        __syncthreads();

        #pragma unroll
        for (int h = 0; h < 4; ++h) {
            const u16* ap = As + h * 4096 + aoff;
            const u16* bp = Bs + h * 4096 + boff;
            bf16x8 af[4], bfv[2];
            #pragma unroll
            for (int r = 0; r < 4; ++r) af[r] = *(const bf16x8*)(ap + r * 512);
            #pragma unroll
            for (int c = 0; c < 2; ++c) bfv[c] = *(const bf16x8*)(bp + c * 512);
            #pragma unroll
            for (int r = 0; r < 4; ++r)
                #pragma unroll
                for (int c = 0; c < 2; ++c)
                    acc[r][c] = __builtin_amdgcn_mfma_f32_16x16x32_bf16(
                        af[r], bfv[c], acc[r][c], 0, 0, 0);
        }
        __syncthreads();
    }

    // epilogue — C/D layout: col = lane&15, row = (lane>>4)*4 + reg
    const int grow0 = mtile * 128 + wr * 64 + quad * 4;
    const int gcol0 = ntile * 128 + wc * 32 + l16;

    if (MODE == 0) {
        if (z < 2) {
            u16* C = z ? Kb : Q;
            #pragma unroll
            for (int r = 0; r < 4; ++r)
                #pragma unroll
                for (int c = 0; c < 2; ++c)
                    #pragma unroll
                    for (int i = 0; i < 4; ++i)
                        C[(size_t)(grow0 + r * 16 + i) * 1024 + gcol0 + c * 16] =
                            f2bf(acc[r][c][i]);
        } else {
            // Vt[b][d][s]: m -> (b,s), n -> d; 4 consecutive i -> consecutive s
            #pragma unroll
            for (int r = 0; r < 4; ++r) {
                int m0 = grow0 + r * 16;
                int b = m0 >> 11, s0 = m0 & 2047;
                #pragma unroll
                for (int c = 0; c < 2; ++c) {
                    int d = gcol0 + c * 16;
                    ushort4 o;
                    o.x = f2bf(acc[r][c][0]); o.y = f2bf(acc[r][c][1]);
                    o.z = f2bf(acc[r][c][2]); o.w = f2bf(acc[r][c][3]);
                    *(ushort4*)(Vt + (size_t)b * (1024 * 2048) + (size_t)d * 2048 + s0) = o;
                }
            }
        }
    } else if (MODE == 1) {
        u16* C = S + (size_t)z * (2048 * 2048);
        float* rs = rowsum + z * 2048;
        const bool diag = (ntile == mtile);
        float rsum[4][4];
        #pragma unroll
        for (int r = 0; r < 4; ++r)
            #pragma unroll
            for (int i = 0; i < 4; ++i) rsum[r][i] = 0.f;
        #pragma unroll
        for (int r = 0; r < 4; ++r)
            #pragma unroll
            for (int c = 0; c < 2; ++c)
                #pragma unroll
                for (int i = 0; i < 4; ++i) {
                    int grow = grow0 + r * 16 + i;
                    int gcol = gcol0 + c * 16;
                    float e = 0.f;
                    if (!diag || gcol <= grow)
                        e = __expf(acc[r][c][i] * 0.03125f - 12.0f);
                    C[(size_t)grow * 2048 + gcol] = f2bf(e);
                    rsum[r][i] += e;
                }
        #pragma unroll
        for (int r = 0; r < 4; ++r)
            #pragma unroll
            for (int i = 0; i < 4; ++i) {
                float s = rsum[r][i];
                s += __shfl_xor(s, 1, 64);
                s += __shfl_xor(s, 2, 64);
                s += __shfl_xor(s, 4, 64);
                s += __shfl_xor(s, 8, 64);
                if (l16 == 0)
                    unsafeAtomicAdd(&rs[grow0 + r * 16 + i], s);
            }
    } else {  // MODE 2
        if (kh == 2) {
            // full tile: normalize and store
            const float* rs = rowsum + z * 2048;
            float* C = out + (size_t)z * (2048 * 1024);
            #pragma unroll
            for (int r = 0; r < 4; ++r)
                #pragma unroll
                for (int i = 0; i < 4; ++i) {
                    int grow = grow0 + r * 16 + i;
                    float inv = 1.0f / rs[grow];
                    #pragma unroll
                    for (int c = 0; c < 2; ++c)
                        C[(size_t)grow * 1024 + gcol0 + c * 16] = acc[r][c][i] * inv;
                }
        } else if (kh == 1) {
            // raw partial straight into out (combined+normalized later)
            float* C = out + (size_t)z * (2048 * 1024);
            #pragma unroll
            for (int r = 0; r < 4; ++r)
                #pragma unroll
                for (int i = 0; i < 4; ++i) {
                    int grow = grow0 + r * 16 + i;
                    #pragma unroll
                    for (int c = 0; c < 2; ++c)
                        C[(size_t)grow * 1024 + gcol0 + c * 16] = acc[r][c][i];
                }
        } else {
            // raw partial into P1 (rows 1024..2047 -> 0..1023)
            float* Pp = P1 + (size_t)z * (1024 * 1024);
            #pragma unroll
            for (int r = 0; r < 4; ++r)
                #pragma unroll
                for (int i = 0; i < 4; ++i) {
                    int prow = grow0 + r * 16 + i - 1024;
                    #pragma unroll
                    for (int c = 0; c < 2; ++c)
                        Pp[(size_t)prow * 1024 + gcol0 + c * 16] = acc[r][c][i];
                }
        }
    }
}

// ---------------------------------------------------------------
// launch
// ---------------------------------------------------------------
extern "C" void kernel_launch(void* const* d_in, const int* in_sizes, int n_in,
                              void* d_out, int out_size, void* d_ws, size_t ws_size,
                              hipStream_t stream) {
    const float* x  = (const float*)d_in[0];
    const float* Wq = (const float*)d_in[1];
    const float* Wk = (const float*)d_in[2];
    const float* Wv = (const float*)d_in[3];
    float* out = (float*)d_out;
    char* ws = (char*)d_ws;
    const size_t Mi = 1u << 20;

    u16* xb  = (u16*)(ws);               // [8192][1024] bf16  16 MiB
    u16* WqT = (u16*)(ws + 16 * Mi);     // [1024][1024] bf16   2 MiB
    u16* WkT = (u16*)(ws + 18 * Mi);
    u16* WvT = (u16*)(ws + 20 * Mi);
    u16* Q   = (u16*)(ws + 22 * Mi);     // [8192][1024] bf16  16 MiB
    u16* Kb  = (u16*)(ws + 38 * Mi);
    u16* Vt  = (u16*)(ws + 54 * Mi);     // [4][1024][2048] bf16 16 MiB
    u16* S   = (u16*)(ws + 70 * Mi);     // [4][2048][2048] bf16 32 MiB (P~)
    float* rowsum = (float*)(ws + 102 * Mi);  // [4][2048] fp32
    float* P1 = (float*)xb;              // split-K partials reuse dead xb (16 MiB)

    // prep: cast x + transpose W + zero rowsum
    prep_kernel<<<11296, 256, 0, stream>>>(
        (const float4*)x, xb, Wq, Wk, Wv, WqT, WkT, WvT, rowsum);

    // QKV projections (z: 0=Q, 1=K, 2=Vt)
    gemm_nt<0><<<1536, 512, 0, stream>>>(xb, WqT, WkT, WvT, Q, Kb, Vt, S, rowsum, out, P1);

    // P~ = exp(QK^T/32 - 12) + rowsum, live causal tiles
    gemm_nt<1><<<768, 512, 0, stream>>>(xb, WqT, WkT, WvT, Q, Kb, Vt, S, rowsum, out, P1);

    // O~ = P~ V, split-K heavy tiles (no atomics, BK128 grain), LPT order
    gemm_nt<2><<<768, 512, 0, stream>>>(xb, WqT, WkT, WvT, Q, Kb, Vt, S, rowsum, out, P1);

    // merge + normalize split-K rows
    combine_kernel<<<4096, 256, 0, stream>>>(
        (const float4*)P1, rowsum, (float4*)out);
}

// Round 5
// 232.731 us; speedup vs baseline: 1.0494x; 1.0494x over previous
//
#include <hip/hip_runtime.h>

typedef unsigned short u16;
typedef __bf16 bf16x8 __attribute__((ext_vector_type(8)));
typedef float f32x4 __attribute__((ext_vector_type(4)));

// ---------- bf16 <-> f32 helpers (RNE) ----------
__device__ __forceinline__ u16 f2bf(float f) {
    union { float f; unsigned int u; } v; v.f = f;
    unsigned int u = v.u;
    return (u16)((u + 0x7FFFu + ((u >> 16) & 1u)) >> 16);
}

// ---------- async global->LDS, 16B per lane ----------
__device__ __forceinline__ void load_lds16(const void* g, void* l) {
    __builtin_amdgcn_global_load_lds(
        (const __attribute__((address_space(1))) unsigned int*)g,
        (__attribute__((address_space(3))) unsigned int*)l,
        16, 0, 0);
}

// ---------------------------------------------------------------
// fused prep: 0..8191 cast x fp32->bf16; 8192..11263 transpose W;
// 11264..11295 zero rowsum (8192 floats).
// ---------------------------------------------------------------
__global__ void __launch_bounds__(256) prep_kernel(
    const float4* __restrict__ X, u16* __restrict__ xb,
    const float* __restrict__ Wq, const float* __restrict__ Wk,
    const float* __restrict__ Wv,
    u16* __restrict__ Oq, u16* __restrict__ Ok, u16* __restrict__ Ov,
    float* __restrict__ rowsum) {
    __shared__ float tile[32][33];
    const int bid = blockIdx.x, tid = threadIdx.x;
    if (bid < 8192) {
        int idx = bid * 256 + tid;
        float4 v = X[idx];
        ushort4 o;
        o.x = f2bf(v.x); o.y = f2bf(v.y); o.z = f2bf(v.z); o.w = f2bf(v.w);
        *(ushort4*)(xb + (size_t)idx * 4) = o;
    } else if (bid < 11264) {
        int id = bid - 8192;
        int zz = id >> 10;
        const float* W = (zz == 0) ? Wq : (zz == 1) ? Wk : Wv;
        u16* O = (zz == 0) ? Oq : (zz == 1) ? Ok : Ov;
        int n0 = (id & 31) * 32, k0 = ((id >> 5) & 31) * 32;
        int tx = tid & 31, ty = tid >> 5;
        #pragma unroll
        for (int j = 0; j < 32; j += 8)
            tile[ty + j][tx] = W[(size_t)(k0 + ty + j) * 1024 + n0 + tx];
        __syncthreads();
        #pragma unroll
        for (int j = 0; j < 32; j += 8)
            O[(size_t)(n0 + ty + j) * 1024 + k0 + tx] = f2bf(tile[tx][ty + j]);
    } else {
        rowsum[(bid - 11264) * 256 + tid] = 0.f;
    }
}

// ---------------------------------------------------------------
// Deep-pipelined NT bf16 GEMM. BM=256, BN=128, BK=64. 512 threads =
// 8 waves in a 4x2 grid; per-wave output 64x64 (acc[4][4] f32x4 = 64
// regs). WHY this shape: the old 128x128 / 2x4 structure was LDS-read
// -BW-bound (21.3 FLOP per LDS byte read x ~61 B/cy/CU = ~800 TF ==
// the measured plateau). 256x128 with 4x2 waves gives A-reread x2 +
// B-reread x4 = 128 KiB per 4.2 MFLOP = 32.8 FLOP/B -> ~1.2 PF LDS
// ceiling.
//
// Double-buffered LDS (96 KiB -> 1 block/CU, 8 waves) with COUNTED
// vmcnt across raw s_barriers (T3/T4): per K-tile:
//   ds_read 16 frags(buf cur) ; lgkmcnt(0) ; barrier     <- buf free
//   stage tile kt+2 into buf cur (6 global_load_lds, left in flight)
//   32 MFMA ; vmcnt(6) (tile kt+1 landed, kt+2 flying) ; barrier
// __syncthreads is NOT used in the loop: it would emit vmcnt(0) and
// drain the prefetch (the documented ~20% stall of the old loop).
//
// Staging swizzle + de-swizzle are byte-identical to the R0-proven
// conflict-free pattern (0 bank conflicts measured), applied per
// 128-row x K32 8KiB section.
//
// MODE 0: QKV proj, 768 blocks = 3 exact rounds, XCD-clustered.
// MODE 1: P~ = exp(QK^T/32 - 12) into S + rowsum. 512 blocks, dead
//         above-diagonal blocks return early (288 live).
// MODE 2: O = (P~ V)/rowsum, K causal-clipped per row-tile, 256 blocks
//         (exactly 1 block/CU), Vt XCD-local.
// ---------------------------------------------------------------
template <int MODE>
__global__ void __launch_bounds__(512) gemm_nt(
    const u16* __restrict__ xb, const u16* __restrict__ WqT,
    const u16* __restrict__ WkT, const u16* __restrict__ WvT,
    u16* __restrict__ Q, u16* __restrict__ Kb,
    u16* __restrict__ Vt, u16* __restrict__ S,
    float* __restrict__ rowsum, float* __restrict__ out) {

    int mtile, ntile, z, kiters;
    const u16 *A, *B;

    if (MODE == 0) {
        int L = blockIdx.x;                      // 768 blocks
        int xcd = L & 7;
        int u = L >> 3;                          // 0..95
        z = u >> 5;                              // 0..2
        int v = u & 31;
        mtile = ((v >> 3) << 3) | xcd;           // 0..31, mtile&7==xcd
        ntile = v & 7;
        A = xb;
        B = (z == 0) ? WqT : (z == 1) ? WkT : WvT;
        kiters = 16;
    } else if (MODE == 1) {
        int L = blockIdx.x;                      // 512 blocks, 288 live
        z = L >> 7;
        int w = L & 127;
        mtile = w >> 4;                          // 0..7  (batch-local)
        ntile = w & 15;                          // 0..15
        if (ntile > 2 * mtile + 1) return;       // fully masked tile
        A = Q  + (size_t)z * (2048 * 1024);
        B = Kb + (size_t)z * (2048 * 1024);
        kiters = 16;
    } else {
        int L = blockIdx.x;                      // 256 blocks
        ntile = L & 7;                           // Vt XCD-local
        int mt = L >> 3;                         // 0..31
        z = mt >> 3;
        mtile = mt & 7;                          // batch-local row-tile
        A = S  + (size_t)z * (2048 * 2048);
        B = Vt + (size_t)z * (1024 * 2048);
        kiters = 4 * (mtile + 1);                // causal K clip
    }

    const int LDA = (MODE == 2) ? 2048 : 1024;

    // LDS: A 2 bufs x 256x64 (32 KiB each), B 2 bufs x 128x64 (16 KiB)
    __shared__ __align__(16) u16 As[32768];
    __shared__ __align__(16) u16 Bs[16384 + MODE * 128];  // mode fingerprint

    const int tid  = threadIdx.x;
    const int lane = tid & 63;
    const int wave = tid >> 6;                   // 0..7
    const int wr = wave >> 1, wc = wave & 1;     // 4 x 2 wave grid

    // staging: 512 threads cover 128 rows x 4 swizzled 16B chunks / section
    const int r0 = tid >> 2;                     // 0..127
    const int kb = (((tid & 3) ^ ((r0 >> 1) & 3))) * 16;

    const char* gA0 = (const char*)(A + (size_t)(mtile * 256 +       r0) * LDA) + kb;
    const char* gA1 = (const char*)(A + (size_t)(mtile * 256 + 128 + r0) * LDA) + kb;
    const char* gB  = (const char*)(B + (size_t)(ntile * 128 +       r0) * LDA) + kb;

    // one K-tile stage: 4 loads for A (2 row-halves x 2 K32 sections),
    // 2 for B. dst = wave-uniform base + lane*16 (linear) per section.
    auto STAGE = [&](int buf, int kt) {
        const size_t off = (size_t)kt * 128;     // 64 K-elems * 2B
        char* a = (char*)As + buf * 32768 + tid * 16;
        char* b = (char*)Bs + buf * 16384 + tid * 16;
        load_lds16(gA0 + off,      a);
        load_lds16(gA0 + off + 64, a + 8192);
        load_lds16(gA1 + off,      a + 16384);
        load_lds16(gA1 + off + 64, a + 24576);
        load_lds16(gB  + off,      b);
        load_lds16(gB  + off + 64, b + 8192);
    };

    // read offsets (u16 units); de-swizzle identical to proven pattern
    const int quad = lane >> 4;
    const int l16  = lane & 15;
    const int ch   = quad ^ ((l16 >> 1) & 3);
    const int aoff = (wr >> 1) * 8192 + ((wr & 1) * 64 + l16) * 32 + ch * 8;
    const int boff = (wc * 64 + l16) * 32 + ch * 8;

    f32x4 acc[4][4] = {};

    // prologue: stage tiles 0,1; wait tile0 only (tile1 stays in flight)
    STAGE(0, 0);
    STAGE(1, 1);
    asm volatile("s_waitcnt vmcnt(6)" ::: "memory");
    __builtin_amdgcn_s_barrier();

    int cur = 0;
    for (int kt = 0; kt < kiters; ++kt) {
        const u16* ap = As + cur * 16384 + aoff;
        const u16* bp = Bs + cur * 8192  + boff;
        bf16x8 af[2][4], bv[2][4];
        #pragma unroll
        for (int h = 0; h < 2; ++h) {
            #pragma unroll
            for (int r = 0; r < 4; ++r) af[h][r] = *(const bf16x8*)(ap + h * 4096 + r * 512);
            #pragma unroll
            for (int c = 0; c < 4; ++c) bv[h][c] = *(const bf16x8*)(bp + h * 4096 + c * 512);
        }
        // my reads landed -> barrier -> everyone's reads landed -> buf free
        asm volatile("s_waitcnt lgkmcnt(0)" ::: "memory");
        __builtin_amdgcn_sched_barrier(0);
        __builtin_amdgcn_s_barrier();
        if (kt + 2 < kiters) STAGE(cur, kt + 2);

        #pragma unroll
        for (int h = 0; h < 2; ++h)
            #pragma unroll
            for (int r = 0; r < 4; ++r)
                #pragma unroll
                for (int c = 0; c < 4; ++c)
                    acc[r][c] = __builtin_amdgcn_mfma_f32_16x16x32_bf16(
                        af[h][r], bv[h][c], acc[r][c], 0, 0, 0);

        // tile kt+1 must have landed in ALL waves before next iter reads it;
        // tile kt+2's 6 loads stay in flight across the barrier.
        if (kt + 2 < kiters) {
            asm volatile("s_waitcnt vmcnt(6)" ::: "memory");
        } else {
            asm volatile("s_waitcnt vmcnt(0)" ::: "memory");
        }
        __builtin_amdgcn_s_barrier();
        cur ^= 1;
    }

    // epilogue — C/D frag layout: col = l16, row = quad*4 + i
    const int grow0 = mtile * 256 + wr * 64 + quad * 4;
    const int gcol0 = ntile * 128 + wc * 64 + l16;

    if (MODE == 0) {
        if (z < 2) {
            u16* C = z ? Kb : Q;
            #pragma unroll
            for (int r = 0; r < 4; ++r)
                #pragma unroll
                for (int c = 0; c < 4; ++c)
                    #pragma unroll
                    for (int i = 0; i < 4; ++i)
                        C[(size_t)(grow0 + r * 16 + i) * 1024 + gcol0 + c * 16] =
                            f2bf(acc[r][c][i]);
        } else {
            // Vt[b][d][s]: m -> (b,s), n -> d; 4 consecutive i -> consecutive s
            #pragma unroll
            for (int r = 0; r < 4; ++r) {
                int m0 = grow0 + r * 16;
                int b = m0 >> 11, s0 = m0 & 2047;
                #pragma unroll
                for (int c = 0; c < 4; ++c) {
                    int d = gcol0 + c * 16;
                    ushort4 o;
                    o.x = f2bf(acc[r][c][0]); o.y = f2bf(acc[r][c][1]);
                    o.z = f2bf(acc[r][c][2]); o.w = f2bf(acc[r][c][3]);
                    *(ushort4*)(Vt + (size_t)b * (1024 * 2048) + (size_t)d * 2048 + s0) = o;
                }
            }
        }
    } else if (MODE == 1) {
        u16* C = S + (size_t)z * (2048 * 2048);
        float* rs = rowsum + z * 2048;
        const bool maskchk = (ntile >= 2 * mtile);   // tile straddles diagonal
        float rsum[4][4];
        #pragma unroll
        for (int r = 0; r < 4; ++r)
            #pragma unroll
            for (int i = 0; i < 4; ++i) rsum[r][i] = 0.f;
        #pragma unroll
        for (int r = 0; r < 4; ++r)
            #pragma unroll
            for (int c = 0; c < 4; ++c)
                #pragma unroll
                for (int i = 0; i < 4; ++i) {
                    int grow = grow0 + r * 16 + i;
                    int gcol = gcol0 + c * 16;
                    float e = 0.f;
                    if (!maskchk || gcol <= grow)
                        e = __expf(acc[r][c][i] * 0.03125f - 12.0f);
                    C[(size_t)grow * 2048 + gcol] = f2bf(e);
                    rsum[r][i] += e;
                }
        #pragma unroll
        for (int r = 0; r < 4; ++r)
            #pragma unroll
            for (int i = 0; i < 4; ++i) {
                float s = rsum[r][i];
                s += __shfl_xor(s, 1, 64);
                s += __shfl_xor(s, 2, 64);
                s += __shfl_xor(s, 4, 64);
                s += __shfl_xor(s, 8, 64);
                if (l16 == 0)
                    unsafeAtomicAdd(&rs[grow0 + r * 16 + i], s);
            }
    } else {  // MODE 2: normalize by row sums
        const float* rs = rowsum + z * 2048;
        float* C = out + (size_t)z * (2048 * 1024);
        #pragma unroll
        for (int r = 0; r < 4; ++r)
            #pragma unroll
            for (int i = 0; i < 4; ++i) {
                int grow = grow0 + r * 16 + i;
                float inv = 1.0f / rs[grow];
                #pragma unroll
                for (int c = 0; c < 4; ++c)
                    C[(size_t)grow * 1024 + gcol0 + c * 16] = acc[r][c][i] * inv;
            }
    }
}

// ---------------------------------------------------------------
// launch
// ---------------------------------------------------------------
extern "C" void kernel_launch(void* const* d_in, const int* in_sizes, int n_in,
                              void* d_out, int out_size, void* d_ws, size_t ws_size,
                              hipStream_t stream) {
    const float* x  = (const float*)d_in[0];
    const float* Wq = (const float*)d_in[1];
    const float* Wk = (const float*)d_in[2];
    const float* Wv = (const float*)d_in[3];
    float* out = (float*)d_out;
    char* ws = (char*)d_ws;
    const size_t Mi = 1u << 20;

    u16* xb  = (u16*)(ws);               // [8192][1024] bf16  16 MiB
    u16* WqT = (u16*)(ws + 16 * Mi);     // [1024][1024] bf16   2 MiB
    u16* WkT = (u16*)(ws + 18 * Mi);
    u16* WvT = (u16*)(ws + 20 * Mi);
    u16* Q   = (u16*)(ws + 22 * Mi);     // [8192][1024] bf16  16 MiB
    u16* Kb  = (u16*)(ws + 38 * Mi);
    u16* Vt  = (u16*)(ws + 54 * Mi);     // [4][1024][2048] bf16 16 MiB
    u16* S   = (u16*)(ws + 70 * Mi);     // [4][2048][2048] bf16 32 MiB (P~)
    float* rowsum = (float*)(ws + 102 * Mi);  // [4][2048] fp32

    // prep: cast x + transpose W + zero rowsum
    prep_kernel<<<11296, 256, 0, stream>>>(
        (const float4*)x, xb, Wq, Wk, Wv, WqT, WkT, WvT, rowsum);

    // QKV projections (z: 0=Q, 1=K, 2=Vt) — 3 exact rounds at 1 block/CU
    gemm_nt<0><<<768, 512, 0, stream>>>(xb, WqT, WkT, WvT, Q, Kb, Vt, S, rowsum, out);

    // P~ = exp(QK^T/32 - 12) + rowsum, live causal tiles
    gemm_nt<1><<<512, 512, 0, stream>>>(xb, WqT, WkT, WvT, Q, Kb, Vt, S, rowsum, out);

    // O = (P~ V)/rowsum, K causal-clipped, Vt XCD-local
    gemm_nt<2><<<256, 512, 0, stream>>>(xb, WqT, WkT, WvT, Q, Kb, Vt, S, rowsum, out);
}